// Round 2
// baseline (400.311 us; speedup 1.0000x reference)
//
#include <hip/hip_runtime.h>
#include <math.h>

#define N_NODES 15000
#define N_EDGES 300000
#define N_RADIAL 8
#define N_SPEC 16
#define NCH 128
#define NY 9
#define RHO_STRIDE 1152   // NY*NCH
#define OUT_COLS 528      // 16 + 128 + 3*128
#define EPB 32            // edges per block (was 64: halve serial chain, 2x TLP)
#define MBLK 12           // nodes per block in node kernel (15000/12 = 1250 exact)
#define KC 32             // K-chunk staged in LDS (32*256 floats = 32 KB)

// ---------------- edge scatter kernel ----------------
// 128 threads = one channel b = n*16+s each. Sorted edge_src -> register
// accumulate, flush with atomics on segment change.
__global__ __launch_bounds__(128) void edge_kernel(
    const float* __restrict__ dist, const float* __restrict__ vec,
    const float* __restrict__ sw,   const float* __restrict__ stab,
    const int* __restrict__ species, const int* __restrict__ esrc,
    const int* __restrict__ edst,   float* __restrict__ rhoi)
{
    const int t = threadIdx.x;          // b in [0,128)
    const int n = t >> 4;               // radial index 0..7
    const int s = t & 15;               // species-feature index 0..15
    const float coefn = (float)(n + 1) * (3.14159265358979323846f / 5.0f);
    const float bnorm = 0.6324555320336759f;   // sqrt(2/cutoff)
    const float s3  = 1.7320508075688772f;
    const float s5  = 2.2360679774997896f;
    const float s15 = 3.872983346207417f;

    int e0 = blockIdx.x * EPB;
    if (e0 >= N_EDGES) return;
    int e1 = min(e0 + EPB, N_EDGES);

    float acc[NY];
    #pragma unroll
    for (int m = 0; m < NY; ++m) acc[m] = 0.0f;

    int cur = esrc[e0];
    for (int e = e0; e < e1; ++e) {
        int src = esrc[e];
        if (src != cur) {   // uniform across block -> no divergence
            float* base = rhoi + (size_t)cur * RHO_STRIDE + t;
            #pragma unroll
            for (int m = 0; m < NY; ++m) {
                atomicAdd(base + m * NCH, acc[m]);
                acc[m] = 0.0f;
            }
            cur = src;
        }
        float r    = dist[e];
        float invr = 1.0f / r;
        float swv  = sw[e];
        float x = vec[3*e+0] * invr;
        float y = vec[3*e+1] * invr;
        float z = vec[3*e+2] * invr;
        int   sp = species[edst[e]];
        float sv = stab[sp * N_SPEC + s];
        float D  = bnorm * __sinf(coefn * r) * invr * swv * sv;

        acc[0] += D;
        acc[1] += D * (s3 * x);
        acc[2] += D * (s3 * y);
        acc[3] += D * (s3 * z);
        acc[4] += D * (s15 * x * y);
        acc[5] += D * (s15 * y * z);
        acc[6] += D * (0.5f * s5 * (3.0f * z * z - 1.0f));
        acc[7] += D * (s15 * x * z);
        acc[8] += D * (0.5f * s15 * (x * x - y * y));
    }
    float* base = rhoi + (size_t)cur * RHO_STRIDE + t;
    #pragma unroll
    for (int m = 0; m < NY; ++m) atomicAdd(base + m * NCH, acc[m]);
}

// ---------------- node kernel (register-tiled GEMM) ----------------
// 256 threads: cp = tid&63 -> output cols {2cp, 2cp+1} and {+128};
// ng = tid>>6 -> nodes 3*ng .. 3*ng+2. Each thread: 3 nodes x 2 col-pairs.
// W chunk (KC x 256) staged in LDS once per kc, reused across all m of l.
// rho a-frags: wave-uniform broadcast global dwordx4 loads (L1-served).

template<int NM>
__device__ __forceinline__ void gemm_part(
    const float* __restrict__ W,      // nbasis x 256, row-major
    const float* __restrict__ rho,    // rhoi + node0*RHO_STRIDE + m0*NCH
    float* __restrict__ sW, int tid, float scale,
    float* __restrict__ outp)         // out + node0*OUT_COLS + 144 + l*128
{
    const int cp = tid & 63;
    const int ng = tid >> 6;

    float accA[NM][3][2];
    float accB[NM][3][2];
    #pragma unroll
    for (int mi = 0; mi < NM; ++mi)
        #pragma unroll
        for (int n = 0; n < 3; ++n) {
            accA[mi][n][0] = 0.f; accA[mi][n][1] = 0.f;
            accB[mi][n][0] = 0.f; accB[mi][n][1] = 0.f;
        }

    for (int kc = 0; kc < NCH; kc += KC) {
        __syncthreads();   // protect sW from previous chunk's readers
        {   // stage W[kc..kc+KC][0..255] -> sW (float4 copies, conflict-free)
            const float4* gw = (const float4*)(W + kc * 256);
            float4* sw4 = (float4*)sW;
            #pragma unroll
            for (int j = 0; j < KC * 64; j += 256)
                sw4[j + tid] = gw[j + tid];
        }
        __syncthreads();

        #pragma unroll
        for (int mi = 0; mi < NM; ++mi) {
            const float* rp = rho + mi * NCH + kc + (size_t)(3 * ng) * RHO_STRIDE;
            #pragma unroll
            for (int k4 = 0; k4 < KC; k4 += 4) {
                float4 a0 = *(const float4*)(rp + k4);
                float4 a1 = *(const float4*)(rp + RHO_STRIDE + k4);
                float4 a2 = *(const float4*)(rp + 2 * RHO_STRIDE + k4);
                #pragma unroll
                for (int kk = 0; kk < 4; ++kk) {
                    const float* wrow = sW + (k4 + kk) * 256 + 2 * cp;
                    float2 bA = *(const float2*)(wrow);
                    float2 bB = *(const float2*)(wrow + 128);
                    float av0 = ((const float*)&a0)[kk];
                    float av1 = ((const float*)&a1)[kk];
                    float av2 = ((const float*)&a2)[kk];
                    accA[mi][0][0] += av0 * bA.x; accA[mi][0][1] += av0 * bA.y;
                    accB[mi][0][0] += av0 * bB.x; accB[mi][0][1] += av0 * bB.y;
                    accA[mi][1][0] += av1 * bA.x; accA[mi][1][1] += av1 * bA.y;
                    accB[mi][1][0] += av1 * bB.x; accB[mi][1][1] += av1 * bB.y;
                    accA[mi][2][0] += av2 * bA.x; accA[mi][2][1] += av2 * bA.y;
                    accB[mi][2][0] += av2 * bB.x; accB[mi][2][1] += av2 * bB.y;
                }
            }
        }
    }

    #pragma unroll
    for (int n = 0; n < 3; ++n) {
        float2 x; x.x = 0.f; x.y = 0.f;
        #pragma unroll
        for (int mi = 0; mi < NM; ++mi) {
            x.x += accA[mi][n][0] * accB[mi][n][0];
            x.y += accA[mi][n][1] * accB[mi][n][1];
        }
        x.x *= scale; x.y *= scale;
        *(float2*)(outp + (size_t)(3 * ng + n) * OUT_COLS + 2 * cp) = x;
    }
}

__global__ __launch_bounds__(256) void node_kernel(
    const float* __restrict__ stab, const int* __restrict__ species,
    const float* __restrict__ W0,   const float* __restrict__ W1,
    const float* __restrict__ W2,   const float* __restrict__ rhoi,
    float* __restrict__ out)
{
    __shared__ float sW[KC * 256];   // 32 KB
    const int tid = threadIdx.x;
    const int node0 = blockIdx.x * MBLK;

    // Head: senc (cols 0..15) + rhoi[:,0,:] (cols 16..143)
    if (tid < 144) {
        #pragma unroll
        for (int n = 0; n < MBLK; ++n) {
            int node = node0 + n;
            float v;
            if (tid < N_SPEC) v = stab[species[node] * N_SPEC + tid];
            else              v = rhoi[(size_t)node * RHO_STRIDE + (tid - N_SPEC)];
            out[(size_t)node * OUT_COLS + tid] = v;
        }
    }

    const float* rbase = rhoi + (size_t)node0 * RHO_STRIDE;
    float* obase = out + (size_t)node0 * OUT_COLS + 144;
    gemm_part<1>(W0, rbase,           sW, tid, 1.0f,                obase);
    gemm_part<3>(W1, rbase + NCH,     sW, tid, 0.5773502691896258f, obase + 128);
    gemm_part<5>(W2, rbase + 4 * NCH, sW, tid, 0.4472135954999579f, obase + 256);
}

extern "C" void kernel_launch(void* const* d_in, const int* in_sizes, int n_in,
                              void* d_out, int out_size, void* d_ws, size_t ws_size,
                              hipStream_t stream) {
    const float* distances = (const float*)d_in[0];
    const float* vec       = (const float*)d_in[1];
    const float* sw        = (const float*)d_in[2];
    const float* stab      = (const float*)d_in[3];
    const float* W0        = (const float*)d_in[4];
    const float* W1        = (const float*)d_in[5];
    const float* W2        = (const float*)d_in[6];
    const int*   species   = (const int*)d_in[7];
    const int*   esrc      = (const int*)d_in[8];
    const int*   edst      = (const int*)d_in[9];
    float* out  = (float*)d_out;
    float* rhoi = (float*)d_ws;                       // 15000*1152 fp32 = 69.12 MB

    hipMemsetAsync(rhoi, 0, (size_t)N_NODES * RHO_STRIDE * sizeof(float), stream);

    int eblocks = (N_EDGES + EPB - 1) / EPB;
    edge_kernel<<<eblocks, 128, 0, stream>>>(distances, vec, sw, stab, species,
                                             esrc, edst, rhoi);

    int nblocks = N_NODES / MBLK;                     // 15000/12 = 1250 exact
    node_kernel<<<nblocks, 256, 0, stream>>>(stab, species, W0, W1, W2, rhoi, out);
}

// Round 3
// 201.767 us; speedup vs baseline: 1.9840x; 1.9840x over previous
//
#include <hip/hip_runtime.h>
#include <math.h>

#define N_NODES 15000
#define NPAD    15008          // 938 blocks * 16 nodes
#define N_EDGES 300000
#define NCH     128
#define RHO_STRIDE 1152        // 9*128
#define OUT_COLS 528           // 16 + 128 + 3*128

typedef _Float16 half8  __attribute__((ext_vector_type(8)));
typedef float    floatx4 __attribute__((ext_vector_type(4)));

// ws layout
#define RHO16_BYTES (NPAD * RHO_STRIDE * 2)            // 34,578,432 (16B aligned)
#define WT_OFF      RHO16_BYTES
#define WT_BYTES    (3 * 256 * 128 * 2)                // 196,608
#define ROWPTR_OFF  (WT_OFF + WT_BYTES)

// ---------- row_ptr: lower_bound of each node id in sorted esrc ----------
__global__ __launch_bounds__(256) void rowptr_kernel(
    const int* __restrict__ esrc, int* __restrict__ row_ptr)
{
    int i = blockIdx.x * 256 + threadIdx.x;
    if (i > NPAD) return;
    int lo = 0, hi = N_EDGES;
    while (lo < hi) { int mid = (lo + hi) >> 1; if (esrc[mid] < i) lo = mid + 1; else hi = mid; }
    row_ptr[i] = lo;
}

// ---------- Wt[l][c][k] = (f16) W_l[k][c] : B-fragment-friendly transpose ----------
__global__ __launch_bounds__(256) void wt_kernel(
    const float* __restrict__ W0, const float* __restrict__ W1,
    const float* __restrict__ W2, _Float16* __restrict__ Wt)
{
    int idx = blockIdx.x * 256 + threadIdx.x;   // 3*256*128 = 98304
    if (idx >= 98304) return;
    int l   = idx >> 15;
    int rem = idx & 32767;
    int c   = rem >> 7;
    int k   = rem & 127;
    const float* W = (l == 0) ? W0 : ((l == 1) ? W1 : W2);
    Wt[idx] = (_Float16)W[k * 256 + c];
}

// ---------- edge kernel: one block per node, no atomics, fp16 stores ----------
__global__ __launch_bounds__(128) void edge_kernel(
    const float* __restrict__ dist, const float* __restrict__ vec,
    const float* __restrict__ sw,   const float* __restrict__ stab,
    const int* __restrict__ species, const int* __restrict__ edst,
    const int* __restrict__ row_ptr, _Float16* __restrict__ rho16)
{
    const int node = blockIdx.x;
    const int t = threadIdx.x;          // channel b = n*16+s
    const int n = t >> 4;
    const int s = t & 15;
    const float coefn = (float)(n + 1) * (3.14159265358979323846f / 5.0f);
    const float bnorm = 0.6324555320336759f;   // sqrt(2/cutoff)
    const float s3  = 1.7320508075688772f;
    const float s5  = 2.2360679774997896f;
    const float s15 = 3.872983346207417f;

    const int lo = row_ptr[node], hi = row_ptr[node + 1];

    float acc[9];
    #pragma unroll
    for (int m = 0; m < 9; ++m) acc[m] = 0.0f;

    for (int e = lo; e < hi; ++e) {
        float r    = dist[e];
        float invr = 1.0f / r;
        float swv  = sw[e];
        float x = vec[3*e+0] * invr;
        float y = vec[3*e+1] * invr;
        float z = vec[3*e+2] * invr;
        int   sp = species[edst[e]];
        float sv = stab[sp * 16 + s];
        float D  = bnorm * __sinf(coefn * r) * invr * swv * sv;

        acc[0] += D;
        acc[1] += D * (s3 * x);
        acc[2] += D * (s3 * y);
        acc[3] += D * (s3 * z);
        acc[4] += D * (s15 * x * y);
        acc[5] += D * (s15 * y * z);
        acc[6] += D * (0.5f * s5 * (3.0f * z * z - 1.0f));
        acc[7] += D * (s15 * x * z);
        acc[8] += D * (0.5f * s15 * (x * x - y * y));
    }
    _Float16* rp = rho16 + (size_t)node * RHO_STRIDE + t;
    #pragma unroll
    for (int m = 0; m < 9; ++m) rp[m * NCH] = (_Float16)acc[m];
}

// ---------- node kernel: MFMA GEMM, 16 nodes/block, no LDS ----------
// Tile M = 16 nodes at fixed spherical index m. Wave w owns x-col tiles
// {2w, 2w+1} (cols 16t..16t+15) and their y partners (+128). For each l:
// hold B-frags in regs (W read once/block), loop m: Cx/Cy via 4 MFMAs each,
// P += Cx*Cy (thread-local xl*yl pairing), store with per-node scale.
__global__ __launch_bounds__(256) void node_kernel(
    const _Float16* __restrict__ rho16, const _Float16* __restrict__ Wt,
    const float* __restrict__ stab, const int* __restrict__ species,
    float* __restrict__ out)
{
    const int tid  = threadIdx.x;
    const int wave = tid >> 6;
    const int lane = tid & 63;
    const int q    = lane >> 4;       // quad
    const int nI   = lane & 15;       // A-row (node within 16) / B-col within tile
    const int node0 = blockIdx.x * 16;

    // ---- head: cols 0..143 (senc | rho m=0) ----
    {
        int nn = tid >> 4;            // 0..15
        int node = node0 + nn;
        if (node < N_NODES) {
            int c0 = (tid & 15) * 9;  // 9 cols per thread
            float* o = out + (size_t)node * OUT_COLS;
            const _Float16* r0 = rho16 + (size_t)node * RHO_STRIDE;
            int sp = species[node];
            #pragma unroll
            for (int j = 0; j < 9; ++j) {
                int c = c0 + j;
                o[c] = (c < 16) ? stab[sp * 16 + c] : (float)r0[c - 16];
            }
        }
    }

    const _Float16* Abase = rho16 + (size_t)(node0 + nI) * RHO_STRIDE + q * 8;
    const int   mstart[3] = {0, 1, 4};
    const int   mcount[3] = {1, 3, 5};
    const float scl[3] = {1.0f, 0.5773502691896258f, 0.4472135954999579f};

    #pragma unroll
    for (int l = 0; l < 3; ++l) {
        const _Float16* Wl = Wt + l * 32768;

        // B-fragments: [cp][half][K], reused across all m of this l
        half8 Bf[2][2][4];
        #pragma unroll
        for (int cp = 0; cp < 2; ++cp)
            #pragma unroll
            for (int h = 0; h < 2; ++h) {
                int c = 16 * (2 * wave + cp) + nI + h * 128;
                const _Float16* bp = Wl + (size_t)c * NCH + q * 8;
                #pragma unroll
                for (int K = 0; K < 4; ++K)
                    Bf[cp][h][K] = *(const half8*)(bp + K * 32);
            }

        floatx4 P0 = {0.f, 0.f, 0.f, 0.f};
        floatx4 P1 = {0.f, 0.f, 0.f, 0.f};

        #pragma unroll
        for (int mi = 0; mi < mcount[l]; ++mi) {
            const _Float16* ap = Abase + (mstart[l] + mi) * NCH;
            half8 Af[4];
            #pragma unroll
            for (int K = 0; K < 4; ++K) Af[K] = *(const half8*)(ap + K * 32);

            #pragma unroll
            for (int cp = 0; cp < 2; ++cp) {
                floatx4 Cx = {0.f, 0.f, 0.f, 0.f};
                floatx4 Cy = {0.f, 0.f, 0.f, 0.f};
                #pragma unroll
                for (int K = 0; K < 4; ++K) {
                    Cx = __builtin_amdgcn_mfma_f32_16x16x32_f16(Af[K], Bf[cp][0][K], Cx, 0, 0, 0);
                    Cy = __builtin_amdgcn_mfma_f32_16x16x32_f16(Af[K], Bf[cp][1][K], Cy, 0, 0, 0);
                }
                if (cp == 0) P0 += Cx * Cy; else P1 += Cx * Cy;
            }
        }

        // store: row = node0 + q*4 + r, col = 144 + l*128 + 16*(2w+cp) + nI
        #pragma unroll
        for (int cp = 0; cp < 2; ++cp) {
            floatx4 P = cp ? P1 : P0;
            int c = 144 + l * NCH + 16 * (2 * wave + cp) + nI;
            #pragma unroll
            for (int r = 0; r < 4; ++r) {
                int node = node0 + q * 4 + r;
                if (node < N_NODES)
                    out[(size_t)node * OUT_COLS + c] = P[r] * scl[l];
            }
        }
    }
}

extern "C" void kernel_launch(void* const* d_in, const int* in_sizes, int n_in,
                              void* d_out, int out_size, void* d_ws, size_t ws_size,
                              hipStream_t stream) {
    const float* distances = (const float*)d_in[0];
    const float* vec       = (const float*)d_in[1];
    const float* sw        = (const float*)d_in[2];
    const float* stab      = (const float*)d_in[3];
    const float* W0        = (const float*)d_in[4];
    const float* W1        = (const float*)d_in[5];
    const float* W2        = (const float*)d_in[6];
    const int*   species   = (const int*)d_in[7];
    const int*   esrc      = (const int*)d_in[8];
    const int*   edst      = (const int*)d_in[9];
    float* out = (float*)d_out;

    _Float16* rho16  = (_Float16*)d_ws;
    _Float16* Wt     = (_Float16*)((char*)d_ws + WT_OFF);
    int*      rowptr = (int*)((char*)d_ws + ROWPTR_OFF);

    rowptr_kernel<<<(NPAD + 256) / 256, 256, 0, stream>>>(esrc, rowptr);
    wt_kernel<<<(98304 + 255) / 256, 256, 0, stream>>>(W0, W1, W2, Wt);
    edge_kernel<<<NPAD, 128, 0, stream>>>(distances, vec, sw, stab, species,
                                          edst, rowptr, rho16);
    node_kernel<<<NPAD / 16, 256, 0, stream>>>(rho16, Wt, stab, species, out);
}

// Round 4
// 169.579 us; speedup vs baseline: 2.3606x; 1.1898x over previous
//
#include <hip/hip_runtime.h>
#include <math.h>

#define N_NODES 15000
#define NPAD    15008          // 938 node-kernel blocks * 16
#define N_EDGES 300000
#define NCH     128
#define RHO_STRIDE 1152        // 9*128
#define OUT_COLS 528           // 16 + 128 + 3*128
#define ES      300032         // padded edge stride for AYt / spE (mult of 32)

typedef _Float16 half8   __attribute__((ext_vector_type(8)));
typedef short    short8  __attribute__((ext_vector_type(8)));
typedef float    floatx4 __attribute__((ext_vector_type(4)));

// ---- workspace layout (all offsets 64B-aligned) ----
#define RHO16_BYTES ((size_t)NPAD * RHO_STRIDE * 2)          // 34,578,432
#define WT_OFF      RHO16_BYTES
#define WT_BYTES    (3 * 256 * 128 * 2)                      // 196,608
#define RP_OFF      (WT_OFF + WT_BYTES)
#define RP_BYTES    61440
#define SPE_OFF     (RP_OFF + RP_BYTES)
#define SPE_BYTES   ((size_t)ES * 2)                         // 600,064
#define AYT_OFF     (SPE_OFF + SPE_BYTES)
#define AYT_BYTES   ((size_t)72 * ES * 2)                    // 43,204,608
#define WS_NEEDED   (AYT_OFF + AYT_BYTES)                    // ~78.6 MB

// ---------- row_ptr: lower_bound of each node id in sorted esrc ----------
__global__ __launch_bounds__(256) void rowptr_kernel(
    const int* __restrict__ esrc, int* __restrict__ row_ptr)
{
    int i = blockIdx.x * 256 + threadIdx.x;
    if (i > NPAD) return;
    int lo = 0, hi = N_EDGES;
    while (lo < hi) { int mid = (lo + hi) >> 1; if (esrc[mid] < i) lo = mid + 1; else hi = mid; }
    row_ptr[i] = lo;
}

// ---------- Wt[l][c][k] = (f16) W_l[k][c] ----------
__global__ __launch_bounds__(256) void wt_kernel(
    const float* __restrict__ W0, const float* __restrict__ W1,
    const float* __restrict__ W2, _Float16* __restrict__ Wt)
{
    int idx = blockIdx.x * 256 + threadIdx.x;   // 3*256*128 = 98304
    if (idx >= 98304) return;
    int l   = idx >> 15;
    int rem = idx & 32767;
    int c   = rem >> 7;
    int k   = rem & 127;
    const float* W = (l == 0) ? W0 : ((l == 1) ? W1 : W2);
    Wt[idx] = (_Float16)W[k * 256 + c];
}

// ---------- E1: per-edge geometry, AYt[row][e] fp16 + spE ----------
__global__ __launch_bounds__(256) void edge_prep_kernel(
    const float* __restrict__ dist, const float* __restrict__ vec,
    const float* __restrict__ sw,   const int* __restrict__ species,
    const int* __restrict__ edst,   _Float16* __restrict__ AYt,
    short* __restrict__ spE)
{
    int e = blockIdx.x * 256 + threadIdx.x;
    if (e >= N_EDGES) return;

    const float bnorm = 0.6324555320336759f;   // sqrt(2/cutoff)
    const float s3  = 1.7320508075688772f;
    const float s5  = 2.2360679774997896f;
    const float s15 = 3.872983346207417f;
    const float cstep = 3.14159265358979323846f / 5.0f;

    float r    = dist[e];
    float invr = 1.0f / r;
    float g    = bnorm * invr * sw[e];
    float x = vec[3*e+0] * invr;
    float y = vec[3*e+1] * invr;
    float z = vec[3*e+2] * invr;

    spE[e] = (short)species[edst[e]];

    float f[8];
    #pragma unroll
    for (int n = 0; n < 8; ++n)
        f[n] = g * __sinf((float)(n + 1) * cstep * r);

    float Y[9];
    Y[0] = 1.0f;
    Y[1] = s3 * x;  Y[2] = s3 * y;  Y[3] = s3 * z;
    Y[4] = s15 * x * y;  Y[5] = s15 * y * z;
    Y[6] = 0.5f * s5 * (3.0f * z * z - 1.0f);
    Y[7] = s15 * x * z;  Y[8] = 0.5f * s15 * (x * x - y * y);

    #pragma unroll
    for (int m = 0; m < 9; ++m)
        #pragma unroll
        for (int n = 0; n < 8; ++n)
            AYt[(size_t)(m * 8 + n) * ES + e] = (_Float16)(Y[m] * f[n]);
}

// ---------- E2: wave-per-node MFMA scatter-GEMM -> rho16 ----------
// rho[80pad x 16] = A(80 x K) * B(K x 16); K-chunks of 32 on aligned edge grid,
// B range-masked to [lo,hi) so straddle/empty segments are correct.
__global__ __launch_bounds__(256) void edge_gemm_kernel(
    const _Float16* __restrict__ AYt, const short* __restrict__ spE,
    const float* __restrict__ stab,  const int* __restrict__ row_ptr,
    _Float16* __restrict__ rho16)
{
    __shared__ _Float16 stabL[64 * 16];
    int tid = threadIdx.x;
    #pragma unroll
    for (int j = 0; j < 4; ++j) stabL[tid * 4 + j] = (_Float16)stab[tid * 4 + j];
    __syncthreads();

    const int wave = tid >> 6, lane = tid & 63;
    const int q = lane >> 4, nI = lane & 15;
    const int node = blockIdx.x * 4 + wave;      // up to NPAD-1; pads have lo==hi
    const int lo = row_ptr[node], hi = row_ptr[node + 1];

    floatx4 acc[5];
    #pragma unroll
    for (int t = 0; t < 5; ++t) acc[t] = (floatx4){0.f, 0.f, 0.f, 0.f};

    for (int k0 = (lo & ~31); k0 < hi; k0 += 32) {
        const int ebase = k0 + q * 8;
        short8 sp8 = *(const short8*)(spE + ebase);   // 16B aligned
        half8 b;
        #pragma unroll
        for (int j = 0; j < 8; ++j) {
            int e = ebase + j;
            bool valid = (e >= lo) && (e < hi);
            int spv = valid ? (int)sp8[j] : 0;
            _Float16 v = stabL[spv * 16 + nI];
            b[j] = valid ? v : (_Float16)0;
        }
        #pragma unroll
        for (int t = 0; t < 5; ++t) {
            int row = t * 16 + nI;
            half8 a = (half8)0;
            if (row < 72) a = *(const half8*)(AYt + (size_t)row * ES + ebase);
            acc[t] = __builtin_amdgcn_mfma_f32_16x16x32_f16(a, b, acc[t], 0, 0, 0);
        }
    }

    _Float16* rp = rho16 + (size_t)node * RHO_STRIDE;
    #pragma unroll
    for (int t = 0; t < 5; ++t)
        #pragma unroll
        for (int r = 0; r < 4; ++r) {
            int row = t * 16 + q * 4 + r;                 // C/D: row=q*4+reg, col=nI
            if (row < 72) {
                int m = row >> 3, nrad = row & 7;
                rp[m * NCH + nrad * 16 + nI] = (_Float16)acc[t][r];
            }
        }
}

// ---------- fallback edge kernel (R3): block-per-node, fp32 acc ----------
__global__ __launch_bounds__(128) void edge_kernel(
    const float* __restrict__ dist, const float* __restrict__ vec,
    const float* __restrict__ sw,   const float* __restrict__ stab,
    const int* __restrict__ species, const int* __restrict__ edst,
    const int* __restrict__ row_ptr, _Float16* __restrict__ rho16)
{
    const int node = blockIdx.x;
    const int t = threadIdx.x;
    const int n = t >> 4;
    const int s = t & 15;
    const float coefn = (float)(n + 1) * (3.14159265358979323846f / 5.0f);
    const float bnorm = 0.6324555320336759f;
    const float s3  = 1.7320508075688772f;
    const float s5  = 2.2360679774997896f;
    const float s15 = 3.872983346207417f;

    const int lo = row_ptr[node], hi = row_ptr[node + 1];
    float acc[9];
    #pragma unroll
    for (int m = 0; m < 9; ++m) acc[m] = 0.0f;

    for (int e = lo; e < hi; ++e) {
        float r    = dist[e];
        float invr = 1.0f / r;
        float swv  = sw[e];
        float x = vec[3*e+0] * invr;
        float y = vec[3*e+1] * invr;
        float z = vec[3*e+2] * invr;
        int   sp = species[edst[e]];
        float sv = stab[sp * 16 + s];
        float D  = bnorm * __sinf(coefn * r) * invr * swv * sv;
        acc[0] += D;
        acc[1] += D * (s3 * x);
        acc[2] += D * (s3 * y);
        acc[3] += D * (s3 * z);
        acc[4] += D * (s15 * x * y);
        acc[5] += D * (s15 * y * z);
        acc[6] += D * (0.5f * s5 * (3.0f * z * z - 1.0f));
        acc[7] += D * (s15 * x * z);
        acc[8] += D * (0.5f * s15 * (x * x - y * y));
    }
    _Float16* rp = rho16 + (size_t)node * RHO_STRIDE + t;
    #pragma unroll
    for (int m = 0; m < 9; ++m) rp[m * NCH] = (_Float16)acc[m];
}

// ---------- node kernel: MFMA GEMM, 16 nodes/block, no LDS (unchanged R3) ----------
__global__ __launch_bounds__(256) void node_kernel(
    const _Float16* __restrict__ rho16, const _Float16* __restrict__ Wt,
    const float* __restrict__ stab, const int* __restrict__ species,
    float* __restrict__ out)
{
    const int tid  = threadIdx.x;
    const int wave = tid >> 6;
    const int lane = tid & 63;
    const int q    = lane >> 4;
    const int nI   = lane & 15;
    const int node0 = blockIdx.x * 16;

    {   // head: cols 0..143 (senc | rho m=0)
        int nn = tid >> 4;
        int node = node0 + nn;
        if (node < N_NODES) {
            int c0 = (tid & 15) * 9;
            float* o = out + (size_t)node * OUT_COLS;
            const _Float16* r0 = rho16 + (size_t)node * RHO_STRIDE;
            int sp = species[node];
            #pragma unroll
            for (int j = 0; j < 9; ++j) {
                int c = c0 + j;
                o[c] = (c < 16) ? stab[sp * 16 + c] : (float)r0[c - 16];
            }
        }
    }

    const _Float16* Abase = rho16 + (size_t)(node0 + nI) * RHO_STRIDE + q * 8;
    const int   mstart[3] = {0, 1, 4};
    const int   mcount[3] = {1, 3, 5};
    const float scl[3] = {1.0f, 0.5773502691896258f, 0.4472135954999579f};

    #pragma unroll
    for (int l = 0; l < 3; ++l) {
        const _Float16* Wl = Wt + l * 32768;

        half8 Bf[2][2][4];
        #pragma unroll
        for (int cp = 0; cp < 2; ++cp)
            #pragma unroll
            for (int h = 0; h < 2; ++h) {
                int c = 16 * (2 * wave + cp) + nI + h * 128;
                const _Float16* bp = Wl + (size_t)c * NCH + q * 8;
                #pragma unroll
                for (int K = 0; K < 4; ++K)
                    Bf[cp][h][K] = *(const half8*)(bp + K * 32);
            }

        floatx4 P0 = {0.f, 0.f, 0.f, 0.f};
        floatx4 P1 = {0.f, 0.f, 0.f, 0.f};

        #pragma unroll
        for (int mi = 0; mi < mcount[l]; ++mi) {
            const _Float16* ap = Abase + (mstart[l] + mi) * NCH;
            half8 Af[4];
            #pragma unroll
            for (int K = 0; K < 4; ++K) Af[K] = *(const half8*)(ap + K * 32);

            #pragma unroll
            for (int cp = 0; cp < 2; ++cp) {
                floatx4 Cx = {0.f, 0.f, 0.f, 0.f};
                floatx4 Cy = {0.f, 0.f, 0.f, 0.f};
                #pragma unroll
                for (int K = 0; K < 4; ++K) {
                    Cx = __builtin_amdgcn_mfma_f32_16x16x32_f16(Af[K], Bf[cp][0][K], Cx, 0, 0, 0);
                    Cy = __builtin_amdgcn_mfma_f32_16x16x32_f16(Af[K], Bf[cp][1][K], Cy, 0, 0, 0);
                }
                if (cp == 0) P0 += Cx * Cy; else P1 += Cx * Cy;
            }
        }

        #pragma unroll
        for (int cp = 0; cp < 2; ++cp) {
            floatx4 P = cp ? P1 : P0;
            int c = 144 + l * NCH + 16 * (2 * wave + cp) + nI;
            #pragma unroll
            for (int r = 0; r < 4; ++r) {
                int node = node0 + q * 4 + r;
                if (node < N_NODES)
                    out[(size_t)node * OUT_COLS + c] = P[r] * scl[l];
            }
        }
    }
}

extern "C" void kernel_launch(void* const* d_in, const int* in_sizes, int n_in,
                              void* d_out, int out_size, void* d_ws, size_t ws_size,
                              hipStream_t stream) {
    const float* distances = (const float*)d_in[0];
    const float* vec       = (const float*)d_in[1];
    const float* sw        = (const float*)d_in[2];
    const float* stab      = (const float*)d_in[3];
    const float* W0        = (const float*)d_in[4];
    const float* W1        = (const float*)d_in[5];
    const float* W2        = (const float*)d_in[6];
    const int*   species   = (const int*)d_in[7];
    const int*   esrc      = (const int*)d_in[8];
    const int*   edst      = (const int*)d_in[9];
    float* out = (float*)d_out;

    _Float16* rho16  = (_Float16*)d_ws;
    _Float16* Wt     = (_Float16*)((char*)d_ws + WT_OFF);
    int*      rowptr = (int*)((char*)d_ws + RP_OFF);

    rowptr_kernel<<<(NPAD + 256) / 256, 256, 0, stream>>>(esrc, rowptr);
    wt_kernel<<<(98304 + 255) / 256, 256, 0, stream>>>(W0, W1, W2, Wt);

    if (ws_size >= WS_NEEDED) {
        short*    spE = (short*)((char*)d_ws + SPE_OFF);
        _Float16* AYt = (_Float16*)((char*)d_ws + AYT_OFF);
        edge_prep_kernel<<<(N_EDGES + 255) / 256, 256, 0, stream>>>(
            distances, vec, sw, species, edst, AYt, spE);
        edge_gemm_kernel<<<NPAD / 4, 256, 0, stream>>>(AYt, spE, stab, rowptr, rho16);
    } else {
        edge_kernel<<<NPAD, 128, 0, stream>>>(distances, vec, sw, stab, species,
                                              edst, rowptr, rho16);
    }

    node_kernel<<<NPAD / 16, 256, 0, stream>>>(rho16, Wt, stab, species, out);
}